// Round 9
// baseline (416.413 us; speedup 1.0000x reference)
//
#include <hip/hip_runtime.h>

typedef __bf16 bf16;
typedef __bf16 bf16x4 __attribute__((ext_vector_type(4)));
typedef __bf16 bf16x8 __attribute__((ext_vector_type(8)));
typedef float  f32x2  __attribute__((ext_vector_type(2)));
typedef float  f32x4  __attribute__((ext_vector_type(4)));
typedef unsigned int u32;
typedef u32 u32x2 __attribute__((ext_vector_type(2)));
typedef u32 u32x4 __attribute__((ext_vector_type(4)));
typedef unsigned short u16;

#define NJ 75
#define SA 104      // A_lds stride (bf16): 208B rows -> ~2-way banks
#define SH 104      // h1 stride
#define SG 136      // gss stride: 272B rows
#define SX 104      // xT stride
#define SR 88       // reds [w][j] f32x2
#define LN_EPS 1e-5f
#define MFMA16(a,b,c) __builtin_amdgcn_mfma_f32_16x16x32_bf16((a),(b),(c),0,0,0)

static __device__ __forceinline__ f32x4 f4z(){ f32x4 v={0.f,0.f,0.f,0.f}; return v; }
static __device__ __forceinline__ u32 pk2(float a, float b){
  u32 ua = (u32)__builtin_bit_cast(u16,(bf16)a);
  u32 ub = (u32)__builtin_bit_cast(u16,(bf16)b);
  return ua | (ub<<16);
}
static __device__ __forceinline__ float lo16f(u32 u){ return __uint_as_float(u<<16); }
static __device__ __forceinline__ float hi16f(u32 u){ return __uint_as_float(u & 0xffff0000u); }

template<int C>
static __device__ __forceinline__ float dppterm(float v){
  return __int_as_float(__builtin_amdgcn_update_dpp(0, __float_as_int(v), C, 0xF, 0xF, true));
}
static __device__ __forceinline__ float red16(float v){
  v += dppterm<0xB1>(v);
  v += dppterm<0x4E>(v);
  v += dppterm<0x141>(v);
  v += dppterm<0x140>(v);
  return v;
}

__global__ __launch_bounds__(512, 4)
void ke8(const float* __restrict__ gx,  const float* __restrict__ gA,
         const float* __restrict__ gW1, const float* __restrict__ gg1, const float* __restrict__ gb1,
         const float* __restrict__ gW2, const float* __restrict__ gg2, const float* __restrict__ gb2,
         const float* __restrict__ gWp, const float* __restrict__ gbp,
         float* __restrict__ gout, int B)
{
  __shared__ __align__(16) bf16 A_lds[80*SA];
  __shared__ __align__(16) bf16 h1[128*SH];
  __shared__ __align__(16) bf16 gss[80*SG];
  __shared__ __align__(16) bf16 xT[4*SX];
  __shared__ __align__(16) float reds[8*SR*2];
  __shared__ __align__(16) float fin[80*2];
  __shared__ __align__(16) float skl[4][256];
  __shared__ __align__(16) float b1l[128];
  __shared__ __align__(16) u32  g2b2[256];
  __shared__ __align__(16) bf16 W1l8[128*8];
  __shared__ __align__(16) u32x2 wpl[256];
  __shared__ __align__(16) float Msh[12];
  __shared__ float xbars[4];

  const int tid = threadIdx.x;
  const int w   = tid >> 6;
  const int l   = tid & 63;
  const int l16 = l & 15;
  const int lg  = l >> 4;

  // ---------------- one-time init ----------------
  for (int i = tid; i < 80*SA; i += 512) {
    const int r = i / SA, c = i - r*SA;
    A_lds[i] = (bf16)((r < NJ && c < NJ) ? gA[r*NJ + c] : 0.f);
  }
  for (int i = tid; i < 128*SH; i += 512) h1[i] = (bf16)0.f;
  for (int i = tid; i < 4*SX; i += 512) xT[i] = (bf16)0.f;
  if (tid < 128) {
    reds[tid*3+0] = gW1[tid*3+0];
    reds[tid*3+1] = gW1[tid*3+1];
    reds[tid*3+2] = gW1[tid*3+2];
    b1l[tid] = gb1[tid];
    fin[tid] = gg1[tid];          // g1 scratch
  }
  if (tid < 256) {
    g2b2[tid] = pk2(gg2[tid], gb2[tid]);
    u32x2 wv = { pk2(gWp[tid*3+0], gWp[tid*3+1]), pk2(gWp[tid*3+2], gbp[tid]) };
    wpl[tid] = wv;
  }
  __syncthreads();
  if (tid < 3) {
    float s = 0.f;
    for (int c = 0; c < 128; ++c) s += reds[c*3 + tid];
    Msh[6 + tid] = s * (1.f/128.f);
  }
  __syncthreads();
  if (tid < 128) {
    float wt0 = reds[tid*3+0] - Msh[6];
    float wt1 = reds[tid*3+1] - Msh[7];
    float wt2 = reds[tid*3+2] - Msh[8];
    const float g1v = fin[tid];
    W1l8[tid*8+0] = (bf16)(g1v*wt0);
    W1l8[tid*8+1] = (bf16)(g1v*wt1);
    W1l8[tid*8+2] = (bf16)(g1v*wt2);
    #pragma unroll
    for (int e = 3; e < 8; ++e) W1l8[tid*8+e] = (bf16)0.f;
    reds[tid*3+0] = wt0; reds[tid*3+1] = wt1; reds[tid*3+2] = wt2;
  }
  __syncthreads();
  if (tid < 6) {
    const int pa[6] = {0,1,2,0,0,1};
    const int pb[6] = {0,1,2,1,2,2};
    float s = 0.f;
    for (int c = 0; c < 128; ++c) s += reds[c*3 + pa[tid]] * reds[c*3 + pb[tid]];
    Msh[tid] = s * (1.f/128.f);
  }

  bf16x8 W2fr[2][4];
  #pragma unroll
  for (int ot = 0; ot < 2; ++ot) {
    const int o = 16*(2*w + ot) + l16;
    #pragma unroll
    for (int ks = 0; ks < 4; ++ks) {
      bf16x8 v;
      #pragma unroll
      for (int e = 0; e < 8; ++e) v[e] = (bf16)gW2[o*128 + 32*ks + 8*lg + e];
      W2fr[ot][ks] = v;
    }
  }
  __syncthreads();
  const float M00 = Msh[0], M11 = Msh[1], M22 = Msh[2];
  const float M01 = Msh[3], M02 = Msh[4], M12 = Msh[5];

  const int  fpb  = (B + 511) >> 9;          // grid = 512
  const long base = (long)blockIdx.x * fpb;

  float xv[4] = {0.f, 0.f, 0.f, 0.f};
  if (w == 5) {
    long fg = base; if (fg >= B) fg = B - 1;
    #pragma unroll
    for (int k = 0; k < 4; ++k) { const int t = l + 64*k; if (t < 225) xv[k] = gx[fg*225 + t]; }
  }
  __syncthreads();

  f32x4 zacc[5][2];
  #pragma unroll
  for (int jt = 0; jt < 5; ++jt) { zacc[jt][0] = f4z(); zacc[jt][1] = f4z(); }

  const int nint = fpb + 2;
  for (int i = 0; i < nint; ++i) {
    // ==================== P1 ====================
    if (i >= 1 && i <= fpb) {
      const bf16* hb = &h1[(16*w + l16)*SH];
      bf16x8 hf0 = *(const bf16x8*)&hb[ 0 + 8*lg];
      bf16x8 hf1 = *(const bf16x8*)&hb[32 + 8*lg];
      bf16x8 hf2 = *(const bf16x8*)&hb[64 + 8*lg];
      #pragma unroll
      for (int jt = 0; jt < 5; ++jt) {
        const bf16* ab = &A_lds[(16*jt + l16)*SA + 8*lg];
        f32x4 ag = f4z();
        ag = MFMA16(hf0, *(const bf16x8*)&ab[ 0], ag);
        ag = MFMA16(hf1, *(const bf16x8*)&ab[32], ag);
        ag = MFMA16(hf2, *(const bf16x8*)&ab[64], ag);
        bf16x4 p;
        #pragma unroll
        for (int r = 0; r < 4; ++r) p[r] = (bf16)ag[r];
        *(bf16x4*)&gss[(16*jt + l16)*SG + 16*w + 4*lg] = p;
      }
    }
    if (w == 5 && i < fpb) {
      float s0 = 0.f, s1 = 0.f, s2 = 0.f;
      #pragma unroll
      for (int k = 0; k < 4; ++k) {
        const int t = l + 64*k;
        if (t < 225) {
          const int j = (t*21846) >> 16;
          const int co = t - 3*j;
          xT[co*SX + j] = (bf16)xv[k];
          if (co == 0) s0 += xv[k]; else if (co == 1) s1 += xv[k]; else s2 += xv[k];
        }
      }
      s0 = red16(s0); s0 += __shfl_xor(s0, 16); s0 += __shfl_xor(s0, 32);
      s1 = red16(s1); s1 += __shfl_xor(s1, 16); s1 += __shfl_xor(s1, 32);
      s2 = red16(s2); s2 += __shfl_xor(s2, 16); s2 += __shfl_xor(s2, 32);
      if (l == 0) { xbars[0] = s0*(1.f/NJ); xbars[1] = s1*(1.f/NJ); xbars[2] = s2*(1.f/NJ); }
    }
    if (w == 6 && i >= 2) {
      float S = 0.f, Q = 0.f;
      #pragma unroll
      for (int ww = 0; ww < 8; ++ww) {
        const f32x2 a = *(const f32x2*)&reds[(ww*SR + l)*2];
        S += a[0]; Q += a[1];
      }
      const float mu = S * (1.f/256.f);
      const float rs = rsqrtf(Q * (1.f/256.f) - mu*mu + LN_EPS);
      f32x2 nr = { -mu*rs, rs };
      *(f32x2*)&fin[l*2] = nr;
    }
    if (w == 7 && i >= 2 && l < 16) {
      const int j2 = 64 + l;
      float S = 0.f, Q = 0.f;
      #pragma unroll
      for (int ww = 0; ww < 8; ++ww) {
        const f32x2 a = *(const f32x2*)&reds[(ww*SR + j2)*2];
        S += a[0]; Q += a[1];
      }
      const float mu = S * (1.f/256.f);
      const float rs = rsqrtf(Q * (1.f/256.f) - mu*mu + LN_EPS);
      f32x2 nr = { -mu*rs, rs };
      *(f32x2*)&fin[j2*2] = nr;
    }
    __syncthreads();

    // ==================== P2 ====================
    if (i >= 2 && i < fpb) {
      // ---- merged steady-state body: S_D + S_C (+ S_A for w<5) in one BB ----
      // S_D(i-2)
      float nmv[5], rsv[5];
      #pragma unroll
      for (int jt = 0; jt < 5; ++jt) {
        const f32x2 nr = *(const f32x2*)&fin[(16*jt + l16)*2];
        nmv[jt] = nr[0]; rsv[jt] = nr[1];
      }
      float os[2][4];
      #pragma unroll
      for (int ot = 0; ot < 2; ++ot) {
        const u32x4 gb = *(const u32x4*)&g2b2[16*(2*w + ot) + 4*lg];
        #pragma unroll
        for (int r = 0; r < 4; ++r) os[ot][r] = 0.f;
        #pragma unroll
        for (int jt = 0; jt < 5; ++jt) {
          #pragma unroll
          for (int r = 0; r < 4; ++r) {
            float v = fmaf(fmaf(zacc[jt][ot][r], rsv[jt], nmv[jt]), lo16f(gb[r]), hi16f(gb[r]));
            v = fmaxf(v, 0.f);
            if (jt == 4) v = (l16 < 11) ? v : 0.f;
            os[ot][r] += v;
          }
        }
        #pragma unroll
        for (int r = 0; r < 4; ++r) os[ot][r] = red16(os[ot][r]);
      }
      {
        const long f = base + (i - 2);
        if (l16 == 0) {
          #pragma unroll
          for (int ot = 0; ot < 2; ++ot) {
            const int o0 = 16*(2*w + ot) + 4*lg;
            const f32x4 sk = *(const f32x4*)&skl[(i-2)&3][o0];
            f32x4 res;
            #pragma unroll
            for (int r = 0; r < 4; ++r) res[r] = os[ot][r]*(1.f/NJ) + sk[r];
            *(f32x4*)&gout[f*256 + o0] = res;
          }
        }
      }
      // S_C(i-1)  (overwrites zacc; scheduler may hoist its ds_reads over S_D)
      __builtin_amdgcn_s_setprio(1);
      #pragma unroll
      for (int jt = 0; jt < 5; ++jt) {
        const bf16* gr = &gss[(16*jt + l16)*SG + 8*lg];
        f32x4 z0 = f4z(), z1 = f4z();
        #pragma unroll
        for (int ks = 0; ks < 4; ++ks) {
          const bf16x8 gf = *(const bf16x8*)&gr[32*ks];
          z0 = MFMA16(W2fr[0][ks], gf, z0);
          z1 = MFMA16(W2fr[1][ks], gf, z1);
        }
        float s = 0.f, q = 0.f;
        #pragma unroll
        for (int r = 0; r < 4; ++r) {
          s += z0[r] + z1[r];
          q = fmaf(z0[r], z0[r], q); q = fmaf(z1[r], z1[r], q);
        }
        s += __shfl_xor(s, 16); q += __shfl_xor(q, 16);
        s += __shfl_xor(s, 32); q += __shfl_xor(q, 32);
        if (lg == 0) { f32x2 sq = {s, q}; *(f32x2*)&reds[(w*SR + 16*jt + l16)*2] = sq; }
        zacc[jt][0] = z0; zacc[jt][1] = z1;
      }
      __builtin_amdgcn_s_setprio(0);
      // S_A(i)
      if (w < 5) {
        const int xrow = (l16 < 3) ? l16 : 3;
        const bf16* xb = &xT[xrow*SX + 8*lg];
        const bf16* ab = &A_lds[(16*w + l16)*SA + 8*lg];
        f32x4 at = f4z();
        at = MFMA16(*(const bf16x8*)&xb[ 0], *(const bf16x8*)&ab[ 0], at);
        at = MFMA16(*(const bf16x8*)&xb[32], *(const bf16x8*)&ab[32], at);
        at = MFMA16(*(const bf16x8*)&xb[64], *(const bf16x8*)&ab[64], at);
        const float a0 = at[0], a1 = at[1], a2 = at[2];
        float qd = fmaf(M00*a0, a0, fmaf(M11*a1, a1, fmaf(M22*a2, a2, LN_EPS)));
        qd = fmaf(2.f*M01*a0, a1, fmaf(2.f*M02*a0, a2, fmaf(2.f*M12*a1, a2, qd)));
        const float rs = rsqrtf(qd);
        bf16x8 hA;
        #pragma unroll
        for (int e = 0; e < 8; ++e) hA[e] = (bf16)0.f;
        hA[0] = (bf16)((lg == 0) ? a0*rs : 0.f);
        hA[1] = (bf16)((lg == 0) ? a1*rs : 0.f);
        hA[2] = (bf16)((lg == 0) ? a2*rs : 0.f);
        #pragma unroll
        for (int nt = 0; nt < 8; ++nt) {
          const bf16x8 wb = *(const bf16x8*)&W1l8[(16*nt + l16)*8];
          const f32x4 hp = MFMA16(hA, wb, f4z());
          const float b1v = b1l[16*nt + l16];
          bf16x4 pkk;
          #pragma unroll
          for (int r = 0; r < 4; ++r) pkk[r] = (bf16)fmaxf(hp[r] + b1v, 0.f);
          *(bf16x4*)&h1[(16*nt + l16)*SH + 16*w + 4*lg] = pkk;
        }
      }
    } else {
      // ---- boundary iterations (i = 0, 1, fpb, fpb+1) ----
      if (i >= 2) {
        float nmv[5], rsv[5];
        #pragma unroll
        for (int jt = 0; jt < 5; ++jt) {
          const f32x2 nr = *(const f32x2*)&fin[(16*jt + l16)*2];
          nmv[jt] = nr[0]; rsv[jt] = nr[1];
        }
        float os[2][4];
        #pragma unroll
        for (int ot = 0; ot < 2; ++ot) {
          const u32x4 gb = *(const u32x4*)&g2b2[16*(2*w + ot) + 4*lg];
          #pragma unroll
          for (int r = 0; r < 4; ++r) os[ot][r] = 0.f;
          #pragma unroll
          for (int jt = 0; jt < 5; ++jt) {
            #pragma unroll
            for (int r = 0; r < 4; ++r) {
              float v = fmaf(fmaf(zacc[jt][ot][r], rsv[jt], nmv[jt]), lo16f(gb[r]), hi16f(gb[r]));
              v = fmaxf(v, 0.f);
              if (jt == 4) v = (l16 < 11) ? v : 0.f;
              os[ot][r] += v;
            }
          }
          #pragma unroll
          for (int r = 0; r < 4; ++r) os[ot][r] = red16(os[ot][r]);
        }
        const long f = base + (i - 2);
        if (l16 == 0 && f < B) {
          #pragma unroll
          for (int ot = 0; ot < 2; ++ot) {
            const int o0 = 16*(2*w + ot) + 4*lg;
            const f32x4 sk = *(const f32x4*)&skl[(i-2)&3][o0];
            f32x4 res;
            #pragma unroll
            for (int r = 0; r < 4; ++r) res[r] = os[ot][r]*(1.f/NJ) + sk[r];
            *(f32x4*)&gout[f*256 + o0] = res;
          }
        }
      }
      if (i >= 1 && i <= fpb) {
        #pragma unroll
        for (int jt = 0; jt < 5; ++jt) {
          const bf16* gr = &gss[(16*jt + l16)*SG + 8*lg];
          f32x4 z0 = f4z(), z1 = f4z();
          #pragma unroll
          for (int ks = 0; ks < 4; ++ks) {
            const bf16x8 gf = *(const bf16x8*)&gr[32*ks];
            z0 = MFMA16(W2fr[0][ks], gf, z0);
            z1 = MFMA16(W2fr[1][ks], gf, z1);
          }
          float s = 0.f, q = 0.f;
          #pragma unroll
          for (int r = 0; r < 4; ++r) {
            s += z0[r] + z1[r];
            q = fmaf(z0[r], z0[r], q); q = fmaf(z1[r], z1[r], q);
          }
          s += __shfl_xor(s, 16); q += __shfl_xor(q, 16);
          s += __shfl_xor(s, 32); q += __shfl_xor(q, 32);
          if (lg == 0) { f32x2 sq = {s, q}; *(f32x2*)&reds[(w*SR + 16*jt + l16)*2] = sq; }
          zacc[jt][0] = z0; zacc[jt][1] = z1;
        }
      }
      if (i < fpb && w < 5) {
        const int xrow = (l16 < 3) ? l16 : 3;
        const bf16* xb = &xT[xrow*SX + 8*lg];
        const bf16* ab = &A_lds[(16*w + l16)*SA + 8*lg];
        f32x4 at = f4z();
        at = MFMA16(*(const bf16x8*)&xb[ 0], *(const bf16x8*)&ab[ 0], at);
        at = MFMA16(*(const bf16x8*)&xb[32], *(const bf16x8*)&ab[32], at);
        at = MFMA16(*(const bf16x8*)&xb[64], *(const bf16x8*)&ab[64], at);
        const float a0 = at[0], a1 = at[1], a2 = at[2];
        float qd = fmaf(M00*a0, a0, fmaf(M11*a1, a1, fmaf(M22*a2, a2, LN_EPS)));
        qd = fmaf(2.f*M01*a0, a1, fmaf(2.f*M02*a0, a2, fmaf(2.f*M12*a1, a2, qd)));
        const float rs = rsqrtf(qd);
        bf16x8 hA;
        #pragma unroll
        for (int e = 0; e < 8; ++e) hA[e] = (bf16)0.f;
        hA[0] = (bf16)((lg == 0) ? a0*rs : 0.f);
        hA[1] = (bf16)((lg == 0) ? a1*rs : 0.f);
        hA[2] = (bf16)((lg == 0) ? a2*rs : 0.f);
        #pragma unroll
        for (int nt = 0; nt < 8; ++nt) {
          const bf16x8 wb = *(const bf16x8*)&W1l8[(16*nt + l16)*8];
          const f32x4 hp = MFMA16(hA, wb, f4z());
          const float b1v = b1l[16*nt + l16];
          bf16x4 pkk;
          #pragma unroll
          for (int r = 0; r < 4; ++r) pkk[r] = (bf16)fmaxf(hp[r] + b1v, 0.f);
          *(bf16x4*)&h1[(16*nt + l16)*SH + 16*w + 4*lg] = pkk;
        }
      }
    }
    // wave 5: issue x(i+1) loads
    if (w == 5 && i + 1 < fpb) {
      long fg = base + i + 1; if (fg >= B) fg = B - 1;
      #pragma unroll
      for (int k = 0; k < 4; ++k) { const int t = l + 64*k; if (t < 225) xv[k] = gx[fg*225 + t]; }
    }
    // wave 6: skip(i)
    if (w == 6 && i < fpb) {
      const float xb0 = xbars[0], xb1 = xbars[1], xb2 = xbars[2];
      #pragma unroll
      for (int k = 0; k < 4; ++k) {
        const int o = l + 64*k;
        const u32x2 wv = wpl[o];
        skl[i&3][o] = fmaf(lo16f(wv[0]), xb0, fmaf(hi16f(wv[0]), xb1, fmaf(lo16f(wv[1]), xb2, hi16f(wv[1]))));
      }
    }
    __syncthreads();
  }
}

extern "C" void kernel_launch(void* const* d_in, const int* in_sizes, int n_in,
                              void* d_out, int out_size, void* d_ws, size_t ws_size,
                              hipStream_t stream) {
  const float* x  = (const float*)d_in[0];
  const float* A  = (const float*)d_in[1];
  const float* W1 = (const float*)d_in[2];
  const float* g1 = (const float*)d_in[3];
  const float* b1 = (const float*)d_in[4];
  const float* W2 = (const float*)d_in[5];
  const float* g2 = (const float*)d_in[6];
  const float* b2 = (const float*)d_in[7];
  const float* Wp = (const float*)d_in[8];
  const float* bp = (const float*)d_in[9];
  float* out = (float*)d_out;
  const int B = in_sizes[0] / 225;
  ke8<<<dim3(512), dim3(512), 0, stream>>>(x, A, W1, g1, b1, W2, g2, b2, Wp, bp, out, B);
}

// Round 10
// 297.781 us; speedup vs baseline: 1.3984x; 1.3984x over previous
//
#include <hip/hip_runtime.h>

typedef __bf16 bf16;
typedef __bf16 bf16x4 __attribute__((ext_vector_type(4)));
typedef __bf16 bf16x8 __attribute__((ext_vector_type(8)));
typedef float  f32x2  __attribute__((ext_vector_type(2)));
typedef float  f32x4  __attribute__((ext_vector_type(4)));
typedef unsigned int u32;
typedef u32 u32x2 __attribute__((ext_vector_type(2)));
typedef u32 u32x4 __attribute__((ext_vector_type(4)));
typedef unsigned short u16;

#define NJ 75
#define SA 104      // A_lds stride (bf16): 208B rows -> ~2-way banks
#define SH 104      // h1 stride
#define SG 136      // gss stride: 272B rows
#define SX 104      // xT stride
#define SR 88       // reds [w][j] f32x2
#define LN_EPS 1e-5f
#define MFMA16(a,b,c) __builtin_amdgcn_mfma_f32_16x16x32_bf16((a),(b),(c),0,0,0)

static __device__ __forceinline__ f32x4 f4z(){ f32x4 v={0.f,0.f,0.f,0.f}; return v; }
static __device__ __forceinline__ u32 pk2(float a, float b){
  u32 ua = (u32)__builtin_bit_cast(u16,(bf16)a);
  u32 ub = (u32)__builtin_bit_cast(u16,(bf16)b);
  return ua | (ub<<16);
}
static __device__ __forceinline__ float lo16f(u32 u){ return __uint_as_float(u<<16); }
static __device__ __forceinline__ float hi16f(u32 u){ return __uint_as_float(u & 0xffff0000u); }

template<int C>
static __device__ __forceinline__ float dppterm(float v){
  return __int_as_float(__builtin_amdgcn_update_dpp(0, __float_as_int(v), C, 0xF, 0xF, true));
}
static __device__ __forceinline__ float red16(float v){
  v += dppterm<0xB1>(v);
  v += dppterm<0x4E>(v);
  v += dppterm<0x141>(v);
  v += dppterm<0x140>(v);
  return v;
}

// NOTE: __launch_bounds__ 2nd arg observed to behave as min BLOCKS/CU on this
// toolchain (R4-R8: value 4 pinned VGPR_Count=64 = 512regs/8waves-per-EU cap;
// R8's bigger body spilled against it -> FETCH 121MB). Use 2 -> 128-VGPR cap;
// occupancy is LDS-capped at 2 blocks/CU regardless.
__global__ __launch_bounds__(512, 2)
void ke9(const float* __restrict__ gx,  const float* __restrict__ gA,
         const float* __restrict__ gW1, const float* __restrict__ gg1, const float* __restrict__ gb1,
         const float* __restrict__ gW2, const float* __restrict__ gg2, const float* __restrict__ gb2,
         const float* __restrict__ gWp, const float* __restrict__ gbp,
         float* __restrict__ gout, int B)
{
  __shared__ __align__(16) bf16 A_lds[80*SA];
  __shared__ __align__(16) bf16 h1[128*SH];
  __shared__ __align__(16) bf16 gss[80*SG];
  __shared__ __align__(16) bf16 xT[4*SX];
  __shared__ __align__(16) float reds[8*SR*2];
  __shared__ __align__(16) float fin[80*2];
  __shared__ __align__(16) float skl[4][256];
  __shared__ __align__(16) float b1l[128];
  __shared__ __align__(16) u32  g2b2[256];
  __shared__ __align__(16) bf16 W1l8[128*8];
  __shared__ __align__(16) u32x2 wpl[256];
  __shared__ __align__(16) float Msh[12];
  __shared__ float xbars[4];

  const int tid = threadIdx.x;
  const int w   = tid >> 6;
  const int l   = tid & 63;
  const int l16 = l & 15;
  const int lg  = l >> 4;

  // ---------------- one-time init ----------------
  for (int i = tid; i < 80*SA; i += 512) {
    const int r = i / SA, c = i - r*SA;
    A_lds[i] = (bf16)((r < NJ && c < NJ) ? gA[r*NJ + c] : 0.f);
  }
  for (int i = tid; i < 128*SH; i += 512) h1[i] = (bf16)0.f;
  for (int i = tid; i < 4*SX; i += 512) xT[i] = (bf16)0.f;
  if (tid < 128) {
    reds[tid*3+0] = gW1[tid*3+0];
    reds[tid*3+1] = gW1[tid*3+1];
    reds[tid*3+2] = gW1[tid*3+2];
    b1l[tid] = gb1[tid];
    fin[tid] = gg1[tid];          // g1 scratch
  }
  if (tid < 256) {
    g2b2[tid] = pk2(gg2[tid], gb2[tid]);
    u32x2 wv = { pk2(gWp[tid*3+0], gWp[tid*3+1]), pk2(gWp[tid*3+2], gbp[tid]) };
    wpl[tid] = wv;
  }
  __syncthreads();
  if (tid < 3) {
    float s = 0.f;
    for (int c = 0; c < 128; ++c) s += reds[c*3 + tid];
    Msh[6 + tid] = s * (1.f/128.f);
  }
  __syncthreads();
  if (tid < 128) {
    float wt0 = reds[tid*3+0] - Msh[6];
    float wt1 = reds[tid*3+1] - Msh[7];
    float wt2 = reds[tid*3+2] - Msh[8];
    const float g1v = fin[tid];
    W1l8[tid*8+0] = (bf16)(g1v*wt0);
    W1l8[tid*8+1] = (bf16)(g1v*wt1);
    W1l8[tid*8+2] = (bf16)(g1v*wt2);
    #pragma unroll
    for (int e = 3; e < 8; ++e) W1l8[tid*8+e] = (bf16)0.f;
    reds[tid*3+0] = wt0; reds[tid*3+1] = wt1; reds[tid*3+2] = wt2;
  }
  __syncthreads();
  if (tid < 6) {
    const int pa[6] = {0,1,2,0,0,1};
    const int pb[6] = {0,1,2,1,2,2};
    float s = 0.f;
    for (int c = 0; c < 128; ++c) s += reds[c*3 + pa[tid]] * reds[c*3 + pb[tid]];
    Msh[tid] = s * (1.f/128.f);
  }

  bf16x8 W2fr[2][4];
  #pragma unroll
  for (int ot = 0; ot < 2; ++ot) {
    const int o = 16*(2*w + ot) + l16;
    #pragma unroll
    for (int ks = 0; ks < 4; ++ks) {
      bf16x8 v;
      #pragma unroll
      for (int e = 0; e < 8; ++e) v[e] = (bf16)gW2[o*128 + 32*ks + 8*lg + e];
      W2fr[ot][ks] = v;
    }
  }
  __syncthreads();
  const float M00 = Msh[0], M11 = Msh[1], M22 = Msh[2];
  const float M01 = Msh[3], M02 = Msh[4], M12 = Msh[5];

  const int  fpb  = (B + 511) >> 9;          // grid = 512
  const long base = (long)blockIdx.x * fpb;

  float xv[4] = {0.f, 0.f, 0.f, 0.f};
  if (w == 5) {
    long fg = base; if (fg >= B) fg = B - 1;
    #pragma unroll
    for (int k = 0; k < 4; ++k) { const int t = l + 64*k; if (t < 225) xv[k] = gx[fg*225 + t]; }
  }
  __syncthreads();

  f32x4 zacc[5][2];
  #pragma unroll
  for (int jt = 0; jt < 5; ++jt) { zacc[jt][0] = f4z(); zacc[jt][1] = f4z(); }

  const int nint = fpb + 2;
  for (int i = 0; i < nint; ++i) {
    // ==================== P1 ====================
    if (i >= 1 && i <= fpb) {
      const bf16* hb = &h1[(16*w + l16)*SH];
      bf16x8 hf0 = *(const bf16x8*)&hb[ 0 + 8*lg];
      bf16x8 hf1 = *(const bf16x8*)&hb[32 + 8*lg];
      bf16x8 hf2 = *(const bf16x8*)&hb[64 + 8*lg];
      #pragma unroll
      for (int jt = 0; jt < 5; ++jt) {
        const bf16* ab = &A_lds[(16*jt + l16)*SA + 8*lg];
        f32x4 ag = f4z();
        ag = MFMA16(hf0, *(const bf16x8*)&ab[ 0], ag);
        ag = MFMA16(hf1, *(const bf16x8*)&ab[32], ag);
        ag = MFMA16(hf2, *(const bf16x8*)&ab[64], ag);
        bf16x4 p;
        #pragma unroll
        for (int r = 0; r < 4; ++r) p[r] = (bf16)ag[r];
        *(bf16x4*)&gss[(16*jt + l16)*SG + 16*w + 4*lg] = p;
      }
    }
    if (w == 5 && i < fpb) {
      float s0 = 0.f, s1 = 0.f, s2 = 0.f;
      #pragma unroll
      for (int k = 0; k < 4; ++k) {
        const int t = l + 64*k;
        if (t < 225) {
          const int j = (t*21846) >> 16;
          const int co = t - 3*j;
          xT[co*SX + j] = (bf16)xv[k];
          if (co == 0) s0 += xv[k]; else if (co == 1) s1 += xv[k]; else s2 += xv[k];
        }
      }
      s0 = red16(s0); s0 += __shfl_xor(s0, 16); s0 += __shfl_xor(s0, 32);
      s1 = red16(s1); s1 += __shfl_xor(s1, 16); s1 += __shfl_xor(s1, 32);
      s2 = red16(s2); s2 += __shfl_xor(s2, 16); s2 += __shfl_xor(s2, 32);
      if (l == 0) { xbars[0] = s0*(1.f/NJ); xbars[1] = s1*(1.f/NJ); xbars[2] = s2*(1.f/NJ); }
    }
    if (w == 6 && i >= 2) {
      float S = 0.f, Q = 0.f;
      #pragma unroll
      for (int ww = 0; ww < 8; ++ww) {
        const f32x2 a = *(const f32x2*)&reds[(ww*SR + l)*2];
        S += a[0]; Q += a[1];
      }
      const float mu = S * (1.f/256.f);
      const float rs = rsqrtf(Q * (1.f/256.f) - mu*mu + LN_EPS);
      f32x2 nr = { -mu*rs, rs };
      *(f32x2*)&fin[l*2] = nr;
    }
    if (w == 7 && i >= 2 && l < 16) {
      const int j2 = 64 + l;
      float S = 0.f, Q = 0.f;
      #pragma unroll
      for (int ww = 0; ww < 8; ++ww) {
        const f32x2 a = *(const f32x2*)&reds[(ww*SR + j2)*2];
        S += a[0]; Q += a[1];
      }
      const float mu = S * (1.f/256.f);
      const float rs = rsqrtf(Q * (1.f/256.f) - mu*mu + LN_EPS);
      f32x2 nr = { -mu*rs, rs };
      *(f32x2*)&fin[j2*2] = nr;
    }
    __syncthreads();

    // ==================== P2 ====================
    if (i >= 2 && i <= fpb) {
      // ---- fused S_D(i-2) + S_C(i-1), interleaved jt-by-jt (low live-set) ----
      float os[2][4];
      #pragma unroll
      for (int ot = 0; ot < 2; ++ot)
        #pragma unroll
        for (int r = 0; r < 4; ++r) os[ot][r] = 0.f;
      const u32x4 gb0 = *(const u32x4*)&g2b2[16*(2*w + 0) + 4*lg];
      const u32x4 gb1 = *(const u32x4*)&g2b2[16*(2*w + 1) + 4*lg];
      #pragma unroll
      for (int jt = 0; jt < 5; ++jt) {
        // issue S_C's LDS reads first; S_D's VALU below fills the latency
        const bf16* gr = &gss[(16*jt + l16)*SG + 8*lg];
        const bf16x8 gf0 = *(const bf16x8*)&gr[ 0];
        const bf16x8 gf1 = *(const bf16x8*)&gr[32];
        const bf16x8 gf2 = *(const bf16x8*)&gr[64];
        const bf16x8 gf3 = *(const bf16x8*)&gr[96];
        const f32x2 nr = *(const f32x2*)&fin[(16*jt + l16)*2];
        // S_D: consume OLD zacc[jt]
        #pragma unroll
        for (int r = 0; r < 4; ++r) {
          float v0 = fmaf(fmaf(zacc[jt][0][r], nr[1], nr[0]), lo16f(gb0[r]), hi16f(gb0[r]));
          float v1 = fmaf(fmaf(zacc[jt][1][r], nr[1], nr[0]), lo16f(gb1[r]), hi16f(gb1[r]));
          v0 = fmaxf(v0, 0.f); v1 = fmaxf(v1, 0.f);
          if (jt == 4) { v0 = (l16 < 11) ? v0 : 0.f; v1 = (l16 < 11) ? v1 : 0.f; }
          os[0][r] += v0; os[1][r] += v1;
        }
        // S_C: z = W2 g^T
        f32x4 z0 = f4z(), z1 = f4z();
        z0 = MFMA16(W2fr[0][0], gf0, z0); z1 = MFMA16(W2fr[1][0], gf0, z1);
        z0 = MFMA16(W2fr[0][1], gf1, z0); z1 = MFMA16(W2fr[1][1], gf1, z1);
        z0 = MFMA16(W2fr[0][2], gf2, z0); z1 = MFMA16(W2fr[1][2], gf2, z1);
        z0 = MFMA16(W2fr[0][3], gf3, z0); z1 = MFMA16(W2fr[1][3], gf3, z1);
        float s = 0.f, q = 0.f;
        #pragma unroll
        for (int r = 0; r < 4; ++r) {
          s += z0[r] + z1[r];
          q = fmaf(z0[r], z0[r], q); q = fmaf(z1[r], z1[r], q);
        }
        s += __shfl_xor(s, 16); q += __shfl_xor(q, 16);
        s += __shfl_xor(s, 32); q += __shfl_xor(q, 32);
        if (lg == 0) { f32x2 sq = {s, q}; *(f32x2*)&reds[(w*SR + 16*jt + l16)*2] = sq; }
        zacc[jt][0] = z0; zacc[jt][1] = z1;
      }
      #pragma unroll
      for (int ot = 0; ot < 2; ++ot)
        #pragma unroll
        for (int r = 0; r < 4; ++r) os[ot][r] = red16(os[ot][r]);
      const long f = base + (i - 2);
      if (l16 == 0 && f < B) {
        #pragma unroll
        for (int ot = 0; ot < 2; ++ot) {
          const int o0 = 16*(2*w + ot) + 4*lg;
          const f32x4 sk = *(const f32x4*)&skl[(i-2)&3][o0];
          f32x4 res;
          #pragma unroll
          for (int r = 0; r < 4; ++r) res[r] = os[ot][r]*(1.f/NJ) + sk[r];
          *(f32x4*)&gout[f*256 + o0] = res;
        }
      }
    } else {
      // ---- boundary: i==1 (S_C only) or i==fpb+1 (S_D only) ----
      if (i >= 2) {
        float nmv[5], rsv[5];
        #pragma unroll
        for (int jt = 0; jt < 5; ++jt) {
          const f32x2 nr = *(const f32x2*)&fin[(16*jt + l16)*2];
          nmv[jt] = nr[0]; rsv[jt] = nr[1];
        }
        float os[2][4];
        #pragma unroll
        for (int ot = 0; ot < 2; ++ot) {
          const u32x4 gb = *(const u32x4*)&g2b2[16*(2*w + ot) + 4*lg];
          #pragma unroll
          for (int r = 0; r < 4; ++r) os[ot][r] = 0.f;
          #pragma unroll
          for (int jt = 0; jt < 5; ++jt) {
            #pragma unroll
            for (int r = 0; r < 4; ++r) {
              float v = fmaf(fmaf(zacc[jt][ot][r], rsv[jt], nmv[jt]), lo16f(gb[r]), hi16f(gb[r]));
              v = fmaxf(v, 0.f);
              if (jt == 4) v = (l16 < 11) ? v : 0.f;
              os[ot][r] += v;
            }
          }
          #pragma unroll
          for (int r = 0; r < 4; ++r) os[ot][r] = red16(os[ot][r]);
        }
        const long f = base + (i - 2);
        if (l16 == 0 && f < B) {
          #pragma unroll
          for (int ot = 0; ot < 2; ++ot) {
            const int o0 = 16*(2*w + ot) + 4*lg;
            const f32x4 sk = *(const f32x4*)&skl[(i-2)&3][o0];
            f32x4 res;
            #pragma unroll
            for (int r = 0; r < 4; ++r) res[r] = os[ot][r]*(1.f/NJ) + sk[r];
            *(f32x4*)&gout[f*256 + o0] = res;
          }
        }
      }
      if (i >= 1 && i <= fpb) {
        #pragma unroll
        for (int jt = 0; jt < 5; ++jt) {
          const bf16* gr = &gss[(16*jt + l16)*SG + 8*lg];
          f32x4 z0 = f4z(), z1 = f4z();
          #pragma unroll
          for (int ks = 0; ks < 4; ++ks) {
            const bf16x8 gf = *(const bf16x8*)&gr[32*ks];
            z0 = MFMA16(W2fr[0][ks], gf, z0);
            z1 = MFMA16(W2fr[1][ks], gf, z1);
          }
          float s = 0.f, q = 0.f;
          #pragma unroll
          for (int r = 0; r < 4; ++r) {
            s += z0[r] + z1[r];
            q = fmaf(z0[r], z0[r], q); q = fmaf(z1[r], z1[r], q);
          }
          s += __shfl_xor(s, 16); q += __shfl_xor(q, 16);
          s += __shfl_xor(s, 32); q += __shfl_xor(q, 32);
          if (lg == 0) { f32x2 sq = {s, q}; *(f32x2*)&reds[(w*SR + 16*jt + l16)*2] = sq; }
          zacc[jt][0] = z0; zacc[jt][1] = z1;
        }
      }
    }
    // S_A(i): x -> h1' (waves 0-4, j-tile = w); analytic LN1
    if (i < fpb && w < 5) {
      const int xrow = (l16 < 3) ? l16 : 3;
      const bf16* xb = &xT[xrow*SX + 8*lg];
      const bf16* ab = &A_lds[(16*w + l16)*SA + 8*lg];
      f32x4 at = f4z();
      at = MFMA16(*(const bf16x8*)&xb[ 0], *(const bf16x8*)&ab[ 0], at);
      at = MFMA16(*(const bf16x8*)&xb[32], *(const bf16x8*)&ab[32], at);
      at = MFMA16(*(const bf16x8*)&xb[64], *(const bf16x8*)&ab[64], at);
      const float a0 = at[0], a1 = at[1], a2 = at[2];
      float qd = fmaf(M00*a0, a0, fmaf(M11*a1, a1, fmaf(M22*a2, a2, LN_EPS)));
      qd = fmaf(2.f*M01*a0, a1, fmaf(2.f*M02*a0, a2, fmaf(2.f*M12*a1, a2, qd)));
      const float rs = rsqrtf(qd);
      bf16x8 hA;
      #pragma unroll
      for (int e = 0; e < 8; ++e) hA[e] = (bf16)0.f;
      hA[0] = (bf16)((lg == 0) ? a0*rs : 0.f);
      hA[1] = (bf16)((lg == 0) ? a1*rs : 0.f);
      hA[2] = (bf16)((lg == 0) ? a2*rs : 0.f);
      #pragma unroll
      for (int nt = 0; nt < 8; ++nt) {
        const bf16x8 wb = *(const bf16x8*)&W1l8[(16*nt + l16)*8];
        const f32x4 hp = MFMA16(hA, wb, f4z());
        const float b1v = b1l[16*nt + l16];
        bf16x4 pkk;
        #pragma unroll
        for (int r = 0; r < 4; ++r) pkk[r] = (bf16)fmaxf(hp[r] + b1v, 0.f);
        *(bf16x4*)&h1[(16*nt + l16)*SH + 16*w + 4*lg] = pkk;
      }
    }
    // wave 5: issue x(i+1) loads
    if (w == 5 && i + 1 < fpb) {
      long fg = base + i + 1; if (fg >= B) fg = B - 1;
      #pragma unroll
      for (int k = 0; k < 4; ++k) { const int t = l + 64*k; if (t < 225) xv[k] = gx[fg*225 + t]; }
    }
    // wave 6: skip(i)
    if (w == 6 && i < fpb) {
      const float xb0 = xbars[0], xb1 = xbars[1], xb2 = xbars[2];
      #pragma unroll
      for (int k = 0; k < 4; ++k) {
        const int o = l + 64*k;
        const u32x2 wv = wpl[o];
        skl[i&3][o] = fmaf(lo16f(wv[0]), xb0, fmaf(hi16f(wv[0]), xb1, fmaf(lo16f(wv[1]), xb2, hi16f(wv[1]))));
      }
    }
    __syncthreads();
  }
}

extern "C" void kernel_launch(void* const* d_in, const int* in_sizes, int n_in,
                              void* d_out, int out_size, void* d_ws, size_t ws_size,
                              hipStream_t stream) {
  const float* x  = (const float*)d_in[0];
  const float* A  = (const float*)d_in[1];
  const float* W1 = (const float*)d_in[2];
  const float* g1 = (const float*)d_in[3];
  const float* b1 = (const float*)d_in[4];
  const float* W2 = (const float*)d_in[5];
  const float* g2 = (const float*)d_in[6];
  const float* b2 = (const float*)d_in[7];
  const float* Wp = (const float*)d_in[8];
  const float* bp = (const float*)d_in[9];
  float* out = (float*)d_out;
  const int B = in_sizes[0] / 225;
  ke9<<<dim3(512), dim3(512), 0, stream>>>(x, A, W1, g1, b1, W2, g2, b2, Wp, bp, out, B);
}

// Round 12
// 246.954 us; speedup vs baseline: 1.6862x; 1.2058x over previous
//
#include <hip/hip_runtime.h>

typedef __bf16 bf16;
typedef __bf16 bf16x4 __attribute__((ext_vector_type(4)));
typedef __bf16 bf16x8 __attribute__((ext_vector_type(8)));
typedef float  f32x2  __attribute__((ext_vector_type(2)));
typedef float  f32x4  __attribute__((ext_vector_type(4)));
typedef unsigned int u32;
typedef u32 u32x2 __attribute__((ext_vector_type(2)));
typedef u32 u32x4 __attribute__((ext_vector_type(4)));
typedef unsigned short u16;

#define NJ 75
#define SA 104      // A_lds stride (bf16): 208B rows -> ~2-way banks
#define SH 88       // h1 stride: 176B rows; k-overrun into next row killed by A zero-cols
#define SG 136      // gss stride: 272B rows
#define SX 104      // xT stride
#define LN_EPS 1e-5f
#define MFMA16(a,b,c) __builtin_amdgcn_mfma_f32_16x16x32_bf16((a),(b),(c),0,0,0)

static __device__ __forceinline__ f32x4 f4z(){ f32x4 v={0.f,0.f,0.f,0.f}; return v; }
static __device__ __forceinline__ u32 pk2(float a, float b){
  u32 ua = (u32)__builtin_bit_cast(u16,(bf16)a);
  u32 ub = (u32)__builtin_bit_cast(u16,(bf16)b);
  return ua | (ub<<16);
}
static __device__ __forceinline__ float lo16f(u32 u){ return __uint_as_float(u<<16); }
static __device__ __forceinline__ float hi16f(u32 u){ return __uint_as_float(u & 0xffff0000u); }

template<int C>
static __device__ __forceinline__ float dppterm(float v){
  return __int_as_float(__builtin_amdgcn_update_dpp(0, __float_as_int(v), C, 0xF, 0xF, true));
}
static __device__ __forceinline__ float red16(float v){
  v += dppterm<0xB1>(v);
  v += dppterm<0x4E>(v);
  v += dppterm<0x141>(v);
  v += dppterm<0x140>(v);
  return v;
}

// launch_bounds(512,4): observed to cap combined regs at 128 (arch 64 + acc 64)
// -> 16 waves/CU with ~80KB LDS. Fastest operating point (R7). (512,2) let regs
// grow -> 8 waves/CU -> slower (R9).
__global__ __launch_bounds__(512, 4)
void ke11(const float* __restrict__ gx,  const float* __restrict__ gA,
          const float* __restrict__ gW1, const float* __restrict__ gg1, const float* __restrict__ gb1,
          const float* __restrict__ gW2, const float* __restrict__ gg2, const float* __restrict__ gb2,
          const float* __restrict__ gWp, const float* __restrict__ gbp,
          float* __restrict__ gout, int B)
{
  __shared__ __align__(16) bf16 A_lds[80*SA];       // 16,640 B
  __shared__ __align__(16) bf16 h1[128*SH + 16];    // 22,592 B
  __shared__ __align__(16) bf16 gss[80*SG];         // 21,760 B
  __shared__ __align__(16) bf16 xT[4*SX];           //    832 B
  __shared__ __align__(16) float red2[16*80*2];     // 10,240 B  [slot][j] f32 (s,q), lane-major j
  __shared__ __align__(16) float fin[80*2];         //    640 B  (nm, rs)
  __shared__ __align__(16) float skl[4][256];       //  4,096 B
  __shared__ __align__(16) float b1l[128];          //    512 B
  __shared__ __align__(16) u32  g2b2[256];          //  1,024 B
  __shared__ __align__(16) bf16 W1l4[128*4];        //  1,024 B
  __shared__ __align__(16) u32x2 wpl[256];          //  2,048 B
  __shared__ __align__(16) float Msh[12];
  __shared__ float xbars[4];

  const int tid = threadIdx.x;
  const int w   = tid >> 6;
  const int l   = tid & 63;
  const int l16 = l & 15;
  const int lg  = l >> 4;

  // ---------------- one-time init ----------------
  for (int i = tid; i < 80*SA; i += 512) {
    const int r = i / SA, c = i - r*SA;
    A_lds[i] = (bf16)((r < NJ && c < NJ) ? gA[r*NJ + c] : 0.f);
  }
  for (int i = tid; i < 128*SH + 16; i += 512) h1[i] = (bf16)0.f;
  for (int i = tid; i < 4*SX; i += 512) xT[i] = (bf16)0.f;
  float* wsc = red2;   // init scratch (384 floats < 2560)
  if (tid < 128) {
    wsc[tid*3+0] = gW1[tid*3+0];
    wsc[tid*3+1] = gW1[tid*3+1];
    wsc[tid*3+2] = gW1[tid*3+2];
    b1l[tid] = gb1[tid];
    fin[tid] = gg1[tid];          // g1 scratch
  }
  if (tid < 256) {
    g2b2[tid] = pk2(gg2[tid], gb2[tid]);
    u32x2 wv = { pk2(gWp[tid*3+0], gWp[tid*3+1]), pk2(gWp[tid*3+2], gbp[tid]) };
    wpl[tid] = wv;
  }
  __syncthreads();
  if (tid < 3) {
    float s = 0.f;
    for (int c = 0; c < 128; ++c) s += wsc[c*3 + tid];
    Msh[6 + tid] = s * (1.f/128.f);
  }
  __syncthreads();
  if (tid < 128) {
    float wt0 = wsc[tid*3+0] - Msh[6];
    float wt1 = wsc[tid*3+1] - Msh[7];
    float wt2 = wsc[tid*3+2] - Msh[8];
    const float g1v = fin[tid];
    W1l4[tid*4+0] = (bf16)(g1v*wt0);
    W1l4[tid*4+1] = (bf16)(g1v*wt1);
    W1l4[tid*4+2] = (bf16)(g1v*wt2);
    W1l4[tid*4+3] = (bf16)0.f;
    wsc[tid*3+0] = wt0; wsc[tid*3+1] = wt1; wsc[tid*3+2] = wt2;
  }
  __syncthreads();
  if (tid < 6) {
    const int pa[6] = {0,1,2,0,0,1};
    const int pb[6] = {0,1,2,1,2,2};
    float s = 0.f;
    for (int c = 0; c < 128; ++c) s += wsc[c*3 + pa[tid]] * wsc[c*3 + pb[tid]];
    Msh[tid] = s * (1.f/128.f);
  }

  bf16x8 W2fr[2][4];
  #pragma unroll
  for (int ot = 0; ot < 2; ++ot) {
    const int o = 16*(2*w + ot) + l16;
    #pragma unroll
    for (int ks = 0; ks < 4; ++ks) {
      bf16x8 v;
      #pragma unroll
      for (int e = 0; e < 8; ++e) v[e] = (bf16)gW2[o*128 + 32*ks + 8*lg + e];
      W2fr[ot][ks] = v;
    }
  }
  __syncthreads();
  const float M00 = Msh[0], M11 = Msh[1], M22 = Msh[2];
  const float M01 = Msh[3], M02 = Msh[4], M12 = Msh[5];

  const int  fpb  = (B + 511) >> 9;          // grid = 512
  const long base = (long)blockIdx.x * fpb;

  float xv[4] = {0.f, 0.f, 0.f, 0.f};
  if (w == 5) {
    long fg = base; if (fg >= B) fg = B - 1;
    #pragma unroll
    for (int k = 0; k < 4; ++k) { const int t = l + 64*k; if (t < 225) xv[k] = gx[fg*225 + t]; }
  }
  __syncthreads();

  f32x4 zacc[5][2];
  #pragma unroll
  for (int jt = 0; jt < 5; ++jt) { zacc[jt][0] = f4z(); zacc[jt][1] = f4z(); }

  const int nint = fpb + 2;
  for (int i = 0; i < nint; ++i) {
    // ==================== P1 ====================
    // S_B(i-1): g = A h1'  (c-slice = wave)
    if (i >= 1 && i <= fpb) {
      const bf16* hb = &h1[(16*w + l16)*SH];
      bf16x8 hf0 = *(const bf16x8*)&hb[ 0 + 8*lg];
      bf16x8 hf1 = *(const bf16x8*)&hb[32 + 8*lg];
      bf16x8 hf2 = *(const bf16x8*)&hb[64 + 8*lg];  // overrun cols x A zero-cols = 0
      #pragma unroll
      for (int jt = 0; jt < 5; ++jt) {
        const bf16* ab = &A_lds[(16*jt + l16)*SA + 8*lg];
        f32x4 ag = f4z();
        ag = MFMA16(hf0, *(const bf16x8*)&ab[ 0], ag);
        ag = MFMA16(hf1, *(const bf16x8*)&ab[32], ag);
        ag = MFMA16(hf2, *(const bf16x8*)&ab[64], ag);
        bf16x4 p;
        #pragma unroll
        for (int r = 0; r < 4; ++r) p[r] = (bf16)ag[r];
        *(bf16x4*)&gss[(16*jt + l16)*SG + 16*w + 4*lg] = p;
      }
    }
    // wave 5: commit xT(i) from regs + xbar(i)
    if (w == 5 && i < fpb) {
      float s0 = 0.f, s1 = 0.f, s2 = 0.f;
      #pragma unroll
      for (int k = 0; k < 4; ++k) {
        const int t = l + 64*k;
        if (t < 225) {
          const int j = (t*21846) >> 16;
          const int co = t - 3*j;
          xT[co*SX + j] = (bf16)xv[k];
          if (co == 0) s0 += xv[k]; else if (co == 1) s1 += xv[k]; else s2 += xv[k];
        }
      }
      s0 = red16(s0); s0 += __shfl_xor(s0, 16); s0 += __shfl_xor(s0, 32);
      s1 = red16(s1); s1 += __shfl_xor(s1, 16); s1 += __shfl_xor(s1, 32);
      s2 = red16(s2); s2 += __shfl_xor(s2, 16); s2 += __shfl_xor(s2, 32);
      if (l == 0) { xbars[0] = s0*(1.f/NJ); xbars[1] = s1*(1.f/NJ); xbars[2] = s2*(1.f/NJ); }
    }
    // waves 6/7: finalize LN2 stats for frame i-2: red2 -> fin
    if (w == 6 && i >= 2) {
      float S = 0.f, Q = 0.f;
      #pragma unroll
      for (int slot = 0; slot < 16; ++slot) {
        const f32x2 a = *(const f32x2*)&red2[(slot*80 + l)*2];
        S += a[0]; Q += a[1];
      }
      const float mu = S * (1.f/256.f);
      const float rs = rsqrtf(Q * (1.f/256.f) - mu*mu + LN_EPS);
      f32x2 nr = { -mu*rs, rs };
      *(f32x2*)&fin[l*2] = nr;
    }
    if (w == 7 && i >= 2 && l < 16) {
      const int j2 = 64 + l;
      float S = 0.f, Q = 0.f;
      #pragma unroll
      for (int slot = 0; slot < 16; ++slot) {
        const f32x2 a = *(const f32x2*)&red2[(slot*80 + j2)*2];
        S += a[0]; Q += a[1];
      }
      const float mu = S * (1.f/256.f);
      const float rs = rsqrtf(Q * (1.f/256.f) - mu*mu + LN_EPS);
      f32x2 nr = { -mu*rs, rs };
      *(f32x2*)&fin[j2*2] = nr;
    }
    __syncthreads();

    // ==================== P2 ====================
    // S_D(i-2): LN2 apply + mean + skip + store (consumes zacc, fin)
    if (i >= 2) {
      float nmv[5], rsv[5];
      #pragma unroll
      for (int jt = 0; jt < 5; ++jt) {
        const f32x2 nr = *(const f32x2*)&fin[(16*jt + l16)*2];
        nmv[jt] = nr[0]; rsv[jt] = nr[1];
      }
      float os[2][4];
      #pragma unroll
      for (int ot = 0; ot < 2; ++ot) {
        const u32x4 gb = *(const u32x4*)&g2b2[16*(2*w + ot) + 4*lg];
        #pragma unroll
        for (int r = 0; r < 4; ++r) os[ot][r] = 0.f;
        #pragma unroll
        for (int jt = 0; jt < 5; ++jt) {
          #pragma unroll
          for (int r = 0; r < 4; ++r) {
            float v = fmaf(fmaf(zacc[jt][ot][r], rsv[jt], nmv[jt]), lo16f(gb[r]), hi16f(gb[r]));
            v = fmaxf(v, 0.f);
            if (jt == 4) v = (l16 < 11) ? v : 0.f;
            os[ot][r] += v;
          }
        }
        #pragma unroll
        for (int r = 0; r < 4; ++r) os[ot][r] = red16(os[ot][r]);
      }
      const long f = base + (i - 2);
      if (l16 == 0 && f < B) {
        #pragma unroll
        for (int ot = 0; ot < 2; ++ot) {
          const int o0 = 16*(2*w + ot) + 4*lg;
          const f32x4 sk = *(const f32x4*)&skl[(i-2)&3][o0];
          f32x4 res;
          #pragma unroll
          for (int r = 0; r < 4; ++r) res[r] = os[ot][r]*(1.f/NJ) + sk[r];
          *(f32x4*)&gout[f*256 + o0] = res;
        }
      }
    }
    // S_C(i-1): z = W2 g^T (o-slice = wave); single xor16, f32 partials
    if (i >= 1 && i <= fpb) {
      #pragma unroll
      for (int jt = 0; jt < 5; ++jt) {
        const bf16* gr = &gss[(16*jt + l16)*SG + 8*lg];
        f32x4 z0 = f4z(), z1 = f4z();
        #pragma unroll
        for (int ks = 0; ks < 4; ++ks) {
          const bf16x8 gf = *(const bf16x8*)&gr[32*ks];
          z0 = MFMA16(W2fr[0][ks], gf, z0);
          z1 = MFMA16(W2fr[1][ks], gf, z1);
        }
        float s = 0.f, q = 0.f;
        #pragma unroll
        for (int r = 0; r < 4; ++r) {
          s += z0[r] + z1[r];
          q = fmaf(z0[r], z0[r], q); q = fmaf(z1[r], z1[r], q);
        }
        s += __shfl_xor(s, 16); q += __shfl_xor(q, 16);
        if ((lg & 1) == 0) {
          const int slot = 2*w + (lg >> 1);
          f32x2 sq = {s, q};
          *(f32x2*)&red2[(slot*80 + 16*jt + l16)*2] = sq;
        }
        zacc[jt][0] = z0; zacc[jt][1] = z1;
      }
    }
    // S_A(i): x -> h1' (waves 0-4, j-tile = w); analytic LN1
    if (i < fpb && w < 5) {
      const int xrow = (l16 < 3) ? l16 : 3;
      const bf16* xb = &xT[xrow*SX + 8*lg];
      const bf16* ab = &A_lds[(16*w + l16)*SA + 8*lg];
      f32x4 at = f4z();
      at = MFMA16(*(const bf16x8*)&xb[ 0], *(const bf16x8*)&ab[ 0], at);
      at = MFMA16(*(const bf16x8*)&xb[32], *(const bf16x8*)&ab[32], at);
      at = MFMA16(*(const bf16x8*)&xb[64], *(const bf16x8*)&ab[64], at);
      const float a0 = at[0], a1 = at[1], a2 = at[2];
      float qd = fmaf(M00*a0, a0, fmaf(M11*a1, a1, fmaf(M22*a2, a2, LN_EPS)));
      qd = fmaf(2.f*M01*a0, a1, fmaf(2.f*M02*a0, a2, fmaf(2.f*M12*a1, a2, qd)));
      const float rs = rsqrtf(qd);
      bf16x8 hA;
      #pragma unroll
      for (int e = 0; e < 8; ++e) hA[e] = (bf16)0.f;
      hA[0] = (bf16)((lg == 0) ? a0*rs : 0.f);
      hA[1] = (bf16)((lg == 0) ? a1*rs : 0.f);
      hA[2] = (bf16)((lg == 0) ? a2*rs : 0.f);
      #pragma unroll
      for (int nt = 0; nt < 8; ++nt) {
        const bf16x4 w4 = *(const bf16x4*)&W1l4[(16*nt + l16)*4];
        bf16x8 wb;
        wb[0] = w4[0]; wb[1] = w4[1]; wb[2] = w4[2]; wb[3] = w4[3];
        wb[4] = w4[3]; wb[5] = w4[3]; wb[6] = w4[3]; wb[7] = w4[3];
        const f32x4 hp = MFMA16(hA, wb, f4z());
        const float b1v = b1l[16*nt + l16];
        bf16x4 pkk;
        #pragma unroll
        for (int r = 0; r < 4; ++r) pkk[r] = (bf16)fmaxf(hp[r] + b1v, 0.f);
        *(bf16x4*)&h1[(16*nt + l16)*SH + 16*w + 4*lg] = pkk;
      }
    }
    // wave 5: issue x(i+1) loads
    if (w == 5 && i + 1 < fpb) {
      long fg = base + i + 1; if (fg >= B) fg = B - 1;
      #pragma unroll
      for (int k = 0; k < 4; ++k) { const int t = l + 64*k; if (t < 225) xv[k] = gx[fg*225 + t]; }
    }
    // wave 6: skip(i)
    if (w == 6 && i < fpb) {
      const float xb0 = xbars[0], xb1 = xbars[1], xb2 = xbars[2];
      #pragma unroll
      for (int k = 0; k < 4; ++k) {
        const int o = l + 64*k;
        const u32x2 wv = wpl[o];
        skl[i&3][o] = fmaf(lo16f(wv[0]), xb0, fmaf(hi16f(wv[0]), xb1, fmaf(lo16f(wv[1]), xb2, hi16f(wv[1]))));
      }
    }
    __syncthreads();
  }
}

extern "C" void kernel_launch(void* const* d_in, const int* in_sizes, int n_in,
                              void* d_out, int out_size, void* d_ws, size_t ws_size,
                              hipStream_t stream) {
  const float* x  = (const float*)d_in[0];
  const float* A  = (const float*)d_in[1];
  const float* W1 = (const float*)d_in[2];
  const float* g1 = (const float*)d_in[3];
  const float* b1 = (const float*)d_in[4];
  const float* W2 = (const float*)d_in[5];
  const float* g2 = (const float*)d_in[6];
  const float* b2 = (const float*)d_in[7];
  const float* Wp = (const float*)d_in[8];
  const float* bp = (const float*)d_in[9];
  float* out = (float*)d_out;
  const int B = in_sizes[0] / 225;
  ke11<<<dim3(512), dim3(512), 0, stream>>>(x, A, W1, g1, b1, W2, g2, b2, Wp, bp, out, B);
}